// Round 8
// baseline (168.191 us; speedup 1.0000x reference)
//
#include <hip/hip_runtime.h>
#include <hip/hip_bf16.h>
#include <cstdint>

// Problem constants
#define DIMC  256
#define NH    8
#define HD    32
#define NPIX  2304       // 48*48
#define BATCH 2
#define KT    32
#define NWAVE 4          // waves per attn block
#define NTW   18         // k-tiles per wave (72 tiles / 4 waves)
#define KPW   576        // keys per wave (NTW*KT)

typedef short s16x8 __attribute__((ext_vector_type(8)));
typedef short s16x4 __attribute__((ext_vector_type(4)));
typedef float f32x4 __attribute__((ext_vector_type(4)));

#define MFMA32(A,B,C) __builtin_amdgcn_mfma_f32_16x16x32_bf16(A,B,C,0,0,0)

// RNA (round-to-nearest-away) bf16 helpers: 1 VALU each.
__device__ inline uint32_t rnau(float x) { return __float_as_uint(x) + 0x8000u; }
__device__ inline uint32_t pk2(uint32_t l_, uint32_t h_) {
  return __builtin_amdgcn_perm(h_, l_, 0x07060302u);  // lo short=l_, hi short=h_
}

// ---------------------------------------------------------------------------
// Pool: x_avg = (x + box3/9 + box5/25 + box7/49)/4, zero-pad, include_pad
// ---------------------------------------------------------------------------
__global__ __launch_bounds__(256) void pool_kernel(const float* __restrict__ x,
                                                   float* __restrict__ xavg) {
  const int plane = blockIdx.x;
  const float* xp = x + (size_t)plane * NPIX;
  __shared__ float sx[NPIX];
  __shared__ float h3[NPIX], h5[NPIX], h7[NPIX];
  const int t = threadIdx.x;
#pragma unroll
  for (int r = 0; r < 9; ++r) sx[r * 256 + t] = xp[r * 256 + t];
  __syncthreads();
#pragma unroll
  for (int r = 0; r < 9; ++r) {
    int p = r * 256 + t;
    int i = p / 48, j = p - i * 48;
    float a3 = 0.f, a5 = 0.f, a7 = 0.f;
#pragma unroll
    for (int dj = -3; dj <= 3; ++dj) {
      int jj = j + dj;
      if (jj < 0 || jj >= 48) continue;
      float v = sx[i * 48 + jj];
      a7 += v;
      if (dj >= -2 && dj <= 2) a5 += v;
      if (dj >= -1 && dj <= 1) a3 += v;
    }
    h3[p] = a3; h5[p] = a5; h7[p] = a7;
  }
  __syncthreads();
#pragma unroll
  for (int r = 0; r < 9; ++r) {
    int p = r * 256 + t;
    int i = p / 48, j = p - i * 48;
    float b3 = 0.f, b5 = 0.f, b7 = 0.f;
#pragma unroll
    for (int di = -3; di <= 3; ++di) {
      int ii = i + di;
      if (ii < 0 || ii >= 48) continue;
      int q = ii * 48 + j;
      b7 += h7[q];
      if (di >= -2 && di <= 2) b5 += h5[q];
      if (di >= -1 && di <= 1) b3 += h3[q];
    }
    xavg[(size_t)plane * NPIX + p] =
        0.25f * (sx[p] + b3 * (1.f / 9.f) + b5 * (1.f / 25.f) + b7 * (1.f / 49.f));
  }
}

// ---------------------------------------------------------------------------
// Fused converts: blocks 0..287 tconv(x), 288..575 tconv(xavg), 576..703 wconv
// All HI-ONLY. UNCHANGED.
// ---------------------------------------------------------------------------
__global__ __launch_bounds__(256) void conv_all(
    const float* __restrict__ x, const float* __restrict__ xavg,
    const float* __restrict__ qw, const float* __restrict__ kvw,
    const float* __restrict__ pw_,
    short* __restrict__ Xh, short* __restrict__ Ah,
    short* __restrict__ Wth) {
  const int bx = blockIdx.x;
  const int t = threadIdx.x;
  if (bx < 576) {
    const float* src = (bx < 288) ? x : xavg;
    short* dhi = (bx < 288) ? Xh : Ah;
    const int bb = (bx < 288) ? bx : bx - 288;
    const int n0 = (bb % 36) * 64, c0 = ((bb / 36) & 3) * 64, b = bb / 144;
    __shared__ __align__(16) float T[64][68];
    {
      const int c = t >> 2, n4 = (t & 3) * 16;
      const float* sp = src + ((size_t)b * DIMC + c0 + c) * NPIX + n0 + n4;
#pragma unroll
      for (int i2 = 0; i2 < 4; ++i2)
        *(f32x4*)&T[c][n4 + i2 * 4] = *(const f32x4*)(sp + i2 * 4);
    }
    __syncthreads();
    {
      const int n = t >> 2, c4 = (t & 3) * 16;
      float v[16];
#pragma unroll
      for (int i = 0; i < 16; ++i) v[i] = T[c4 + i][n];
      uint32_t a[16];
#pragma unroll
      for (int i = 0; i < 16; ++i) a[i] = rnau(v[i]);
      union { s16x8 s; uint32_t u[4]; } H0, H1;
#pragma unroll
      for (int j = 0; j < 4; ++j) {
        H0.u[j] = pk2(a[2 * j], a[2 * j + 1]);
        H1.u[j] = pk2(a[8 + 2 * j], a[8 + 2 * j + 1]);
      }
      const size_t off = ((size_t)b * NPIX + n0 + n) * DIMC + c0 + c4;
      *(s16x8*)(dhi + off) = H0.s; *(s16x8*)(dhi + off + 8) = H1.s;
    }
  } else {
    const int idx = ((bx - 576) * 256 + t) * 8;
    const float* s;
    int off;
    if (idx < 65536)       { s = qw;  off = idx; }
    else if (idx < 196608) { s = kvw; off = idx - 65536; }
    else                   { s = pw_; off = idx - 196608; }
    f32x4 x0 = *(const f32x4*)(s + off);
    f32x4 x1 = *(const f32x4*)(s + off + 4);
    float v[8] = {x0[0], x0[1], x0[2], x0[3], x1[0], x1[1], x1[2], x1[3]};
    uint32_t a[8];
#pragma unroll
    for (int i = 0; i < 8; ++i) a[i] = rnau(v[i]);
    union { s16x8 s; uint32_t u[4]; } H;
#pragma unroll
    for (int j = 0; j < 4; ++j) H.u[j] = pk2(a[2 * j], a[2 * j + 1]);
    *(s16x8*)(Wth + idx) = H.s;
  }
}

// ---------------------------------------------------------------------------
// QKV GEMM. Q/K epilogues unchanged. V epilogue writes the n-dimension
// PERMUTED within each 32-key tile (bijection mu):
//   stored pos p = 8g+r   holds logical key 4g+r
//   stored pos p = 8g+4+r holds logical key 16+4g+r
// (R6-verified: makes attn's S fragment directly the PV B-operand.)
// ---------------------------------------------------------------------------
__global__ __launch_bounds__(128) void gemm_qkv_hi(
    const short* __restrict__ Wth,
    const float* __restrict__ q_b, const float* __restrict__ kv_b,
    const short* __restrict__ Xh, const short* __restrict__ Ah,
    short* __restrict__ Qhi, short* __restrict__ Khi, short* __restrict__ Vhi,
    float qscale) {
  __shared__ __align__(16) float Cl[32][68];
  const int by = blockIdx.y;
  const bool isQ = (by < 8);
  const int o0 = isQ ? by * 32 : (by - 8) * 32;
  const short* Wh = isQ ? Wth : Wth + 65536;
  const float* bias = isQ ? q_b : kv_b;
  const short* Inh = isQ ? Xh : Ah;
  const float scale = isQ ? qscale : 1.0f;
  short* d1 = isQ ? Qhi : Khi;   // used when o0 < 256 (Q or K)
  const int n0 = blockIdx.x * 64;
  const int b  = blockIdx.z;

  const int tid = threadIdx.x;
  const int wave = tid >> 6, lane = tid & 63;
  const int g = lane >> 4, q = lane & 15;

  const short* wph = Wh + ((o0 + wave * 16 + q) * DIMC + g * 8);
  const short* iph = Inh + ((size_t)(b * NPIX + n0 + q) * DIMC + g * 8);

  f32x4 acc[4] = {{0,0,0,0},{0,0,0,0},{0,0,0,0},{0,0,0,0}};
#pragma unroll
  for (int c0 = 0; c0 < DIMC; c0 += 32) {
    s16x8 ah = *(const s16x8*)(wph + c0);
#pragma unroll
    for (int st = 0; st < 4; ++st) {
      s16x8 bh_ = *(const s16x8*)(iph + (size_t)st * 16 * DIMC + c0);
      acc[st] = MFMA32(ah, bh_, acc[st]);
    }
  }
#pragma unroll
  for (int st = 0; st < 4; ++st)
#pragma unroll
    for (int r = 0; r < 4; ++r)
      Cl[wave * 16 + g * 4 + r][st * 16 + q] = acc[st][r];
  __syncthreads();

  if (o0 < 256) {
    // Q or K: (C+bias)*scale, hi-only, layout [bh][n][32]
    const int n = tid >> 1, oq = tid & 1;
    const int h = o0 >> 5;
    const float* bp = bias + o0 + oq * 16;
    float v[16];
#pragma unroll
    for (int i = 0; i < 16; ++i) v[i] = (Cl[oq * 16 + i][n] + bp[i]) * scale;
    uint32_t a[16];
#pragma unroll
    for (int i = 0; i < 16; ++i) a[i] = rnau(v[i]);
    union { s16x8 s; uint32_t u[4]; } H0, H1;
#pragma unroll
    for (int j = 0; j < 4; ++j) {
      H0.u[j] = pk2(a[2 * j], a[2 * j + 1]);
      H1.u[j] = pk2(a[8 + 2 * j], a[8 + 2 * j + 1]);
    }
    const size_t off = ((size_t)((b * 8 + h) * NPIX + n0 + n)) * HD + oq * 16;
    *(s16x8*)(d1 + off) = H0.s; *(s16x8*)(d1 + off + 8) = H1.s;
  } else {
    // V hi-only: dst [bh][d][n], n mu-permuted within each 32-tile.
    const int o = tid >> 2, nc = (tid & 3) * 16;
    const int h = (o0 - 256) >> 5;
    const float bv = bias[o0 + o];
    float v[16];
#pragma unroll
    for (int i2 = 0; i2 < 4; ++i2) {
      f32x4 t4 = *(const f32x4*)&Cl[o][nc + i2 * 4];
      v[i2 * 4 + 0] = t4[0] + bv; v[i2 * 4 + 1] = t4[1] + bv;
      v[i2 * 4 + 2] = t4[2] + bv; v[i2 * 4 + 3] = t4[3] + bv;
    }
    uint32_t a[16];
#pragma unroll
    for (int i = 0; i < 16; ++i) a[i] = rnau(v[i]);
    short* po = Vhi + ((size_t)((b * 8 + h) * HD + o)) * NPIX + n0 + (nc & 32);
    const int phase = (nc & 16) ? 4 : 0;
#pragma unroll
    for (int j = 0; j < 4; ++j) {
      uint2 wv;
      wv.x = pk2(a[4 * j], a[4 * j + 1]);
      wv.y = pk2(a[4 * j + 2], a[4 * j + 3]);
      *(uint2*)(po + phase + 8 * j) = wv;
    }
  }
}

// ---------------------------------------------------------------------------
// MFMA flash attention: 16 q-rows per block (half-tile), 4-wave intra-block
// split-K, in-register P (mu-permuted V), XCD swizzle. 2304 blocks -> 2x the
// wave supply of R6 with HALF the per-wave serial chain per step (5 MFMA +
// 8 exp2 + 12 pack-VALU); pipeline length stays 18 steps so the prefetch
// prologue stays amortized (R4 lesson). No min-waves clamp (R3 lesson).
// ---------------------------------------------------------------------------
__global__ __launch_bounds__(256) void attn_fused(
    const short* __restrict__ Qhi,   // [bh][n][32]
    const short* __restrict__ Khi,   // [bh][n][32]
    const short* __restrict__ Vhi,   // [bh][32][N] (n mu-permuted per 32-tile)
    short* __restrict__ zh) {        // [b][pix][256] scrambled
  const int li = blockIdx.x;         // 0..2303
  const int r288 = li >> 3;          // 0..287
  const int bh = 2 * (li & 7) + (r288 >= 144 ? 1 : 0);
  const int qb = (r288 >= 144) ? r288 - 144 : r288;  // 16-row q block
  const int tid = threadIdx.x;
  const int wave = tid >> 6, lane = tid & 63;
  const int g = lane >> 4, q = lane & 15;
  const int base = qb * 16;

  // LDS: final reduction only. [4 waves][64 lanes][12 f32] = 12288 B.
  __shared__ __align__(16) float R[4][64][12];

  const size_t qoff = ((size_t)bh * NPIX + base + q) * HD + g * 8;
  const s16x8 qhA = *(const s16x8*)(Qhi + qoff);

  const short* kp = Khi + ((size_t)bh * NPIX + wave * KPW + q) * HD + g * 8;
  const short* vp = Vhi + ((size_t)bh * HD + q) * NPIX + wave * KPW + g * 8;

  const f32x4 Z4 = {0.f, 0.f, 0.f, 0.f};
  f32x4 OA0 = Z4, OA1 = Z4, LA = Z4;
  s16x8 kb[3][2], vb[3][2], pfA, vp0, vp1;

  union { s16x8 s; uint32_t u[4]; } ONE, ZZ;
  ONE.u[0] = 0x3F803F80u; ONE.u[1] = 0x3F803F80u;
  ONE.u[2] = 0x3F803F80u; ONE.u[3] = 0x3F803F80u;
  ZZ.u[0] = 0; ZZ.u[1] = 0; ZZ.u[2] = 0; ZZ.u[3] = 0;
  const s16x8 ones = ONE.s;
  pfA = ZZ.s;                      // P=0 -> first O/L MFMAs add exact 0
  vp0 = ones; vp1 = ones;          // finite (avoid NaN*0)

  kb[0][0] = *(const s16x8*)(kp);
  kb[0][1] = *(const s16x8*)(kp + 16 * HD);
  vb[0][0] = *(const s16x8*)(vp);
  vb[0][1] = *(const s16x8*)(vp + 16 * NPIX);
  kb[1][0] = *(const s16x8*)(kp + KT * HD);
  kb[1][1] = *(const s16x8*)(kp + KT * HD + 16 * HD);
  vb[1][0] = *(const s16x8*)(vp + KT);
  vb[1][1] = *(const s16x8*)(vp + KT + 16 * NPIX);

#define ATTN_STEP(CUR, NX2, T)                                                \
  {                                                                           \
    if ((T) + 2 < NTW) {                                                      \
      const short* kpn = kp + ((T) + 2) * (KT * HD);                          \
      const short* vpn = vp + ((T) + 2) * KT;                                 \
      kb[NX2][0] = *(const s16x8*)(kpn);                                      \
      kb[NX2][1] = *(const s16x8*)(kpn + 16 * HD);                            \
      vb[NX2][0] = *(const s16x8*)(vpn);                                      \
      vb[NX2][1] = *(const s16x8*)(vpn + 16 * NPIX);                          \
    }                                                                         \
    f32x4 SA0 = MFMA32(kb[CUR][0], qhA, Z4);                                  \
    f32x4 SA1 = MFMA32(kb[CUR][1], qhA, Z4);                                  \
    OA0 = MFMA32(vp0, pfA, OA0);                                              \
    OA1 = MFMA32(vp1, pfA, OA1);                                              \
    LA  = MFMA32(ones, pfA, LA);                                              \
    {                                                                         \
      f32x4 p0, p1;                                                           \
      p0[0] = exp2f(SA0[0]); p0[1] = exp2f(SA0[1]);                           \
      p0[2] = exp2f(SA0[2]); p0[3] = exp2f(SA0[3]);                           \
      p1[0] = exp2f(SA1[0]); p1[1] = exp2f(SA1[1]);                           \
      p1[2] = exp2f(SA1[2]); p1[3] = exp2f(SA1[3]);                           \
      union { s16x8 s; uint32_t u[4]; } PA;                                   \
      PA.u[0] = pk2(rnau(p0[0]), rnau(p0[1]));                                \
      PA.u[1] = pk2(rnau(p0[2]), rnau(p0[3]));                                \
      PA.u[2] = pk2(rnau(p1[0]), rnau(p1[1]));                                \
      PA.u[3] = pk2(rnau(p1[2]), rnau(p1[3]));                                \
      pfA = PA.s;                                                             \
    }                                                                         \
    vp0 = vb[CUR][0]; vp1 = vb[CUR][1];                                       \
  }

#pragma unroll 1
  for (int tt = 0; tt < NTW; tt += 3) {
    ATTN_STEP(0, 2, tt);
    ATTN_STEP(1, 0, tt + 1);
    ATTN_STEP(2, 1, tt + 2);
  }
#undef ATTN_STEP

  // Tail: consume P of the wave's last tile
  OA0 = MFMA32(vp0, pfA, OA0);
  OA1 = MFMA32(vp1, pfA, OA1);
  LA  = MFMA32(ones, pfA, LA);

  {
    float* rw = &R[wave][lane][0];
    *(f32x4*)&rw[0] = OA0;    // d = g*4+r
    *(f32x4*)&rw[4] = OA1;    // d = 16+g*4+r
    rw[8] = LA[0];            // L rows identical -> LA[0] = L[q-row]
  }
  __syncthreads();
  {
    // 256 threads: lane-slot l2, eg in 0..3 picks 2 consecutive O-elements.
    const int l2 = tid & 63, eg = tid >> 6;
    const int g2 = l2 >> 4, q2 = l2 & 15;
    const int e0 = eg * 2;    // element 0..7 (0..3 in OA0, 4..7 in OA1)
    float s0 = 0.f, s1 = 0.f, Lt = 0.f;
#pragma unroll
    for (int w = 0; w < NWAVE; ++w) {
      const float* rw = &R[w][l2][0];
      s0 += rw[e0];
      s1 += rw[e0 + 1];
      Lt += rw[8];
    }
    const float inv = 1.f / Lt;
    const int h = bh & 7, b = bh >> 3;
    const int n = base + q2;
    const int d0 = (e0 < 4) ? (g2 * 4 + e0) : (16 + g2 * 4 + (e0 - 4));
    const int c = n / 9, r = n - c * 9;
    short* zp = zh + ((size_t)(b * NPIX + r * 256 + h * HD + d0)) * DIMC + c;
    zp[0]    = (short)(rnau(s0 * inv) >> 16);
    zp[DIMC] = (short)(rnau(s1 * inv) >> 16);
  }
}

// ---------------------------------------------------------------------------
// PROJ GEMM: single MFMA/tile (Wh*Zh). fp32 out + bias. UNCHANGED.
// ---------------------------------------------------------------------------
__global__ __launch_bounds__(128) void gemm_proj_hi(
    const short* __restrict__ Wh,
    const float* __restrict__ bias,
    const short* __restrict__ Zh,
    float* __restrict__ out) {
  __shared__ __align__(16) float Cl[32][68];
  const int n0 = blockIdx.x * 64;
  const int o0 = blockIdx.y * 32;
  const int b  = blockIdx.z;
  const int tid = threadIdx.x;
  const int wave = tid >> 6, lane = tid & 63;
  const int g = lane >> 4, q = lane & 15;

  const short* wph = Wh + ((o0 + wave * 16 + q) * DIMC + g * 8);
  const short* iph = Zh + ((size_t)(b * NPIX + n0 + q) * DIMC + g * 8);

  f32x4 acc[4] = {{0,0,0,0},{0,0,0,0},{0,0,0,0},{0,0,0,0}};
#pragma unroll
  for (int c0 = 0; c0 < DIMC; c0 += 32) {
    s16x8 ah = *(const s16x8*)(wph + c0);
#pragma unroll
    for (int st = 0; st < 4; ++st) {
      s16x8 bh_ = *(const s16x8*)(iph + (size_t)st * 16 * DIMC + c0);
      acc[st] = MFMA32(ah, bh_, acc[st]);
    }
  }
#pragma unroll
  for (int st = 0; st < 4; ++st)
#pragma unroll
    for (int r = 0; r < 4; ++r)
      Cl[wave * 16 + g * 4 + r][st * 16 + q] = acc[st][r];
  __syncthreads();

  const int o = tid >> 2, nc = (tid & 3) * 16;
  const float bv = bias[o0 + o];
  float* op = out + ((size_t)b * DIMC + o0 + o) * NPIX + n0 + nc;
#pragma unroll
  for (int i2 = 0; i2 < 4; ++i2) {
    f32x4 v = *(const f32x4*)&Cl[o][nc + i2 * 4];
    v[0] += bv; v[1] += bv; v[2] += bv; v[3] += bv;
    *(f32x4*)(op + i2 * 4) = v;
  }
}

// ---------------------------------------------------------------------------
extern "C" void kernel_launch(void* const* d_in, const int* in_sizes, int n_in,
                              void* d_out, int out_size, void* d_ws, size_t ws_size,
                              hipStream_t stream) {
  const float* x      = (const float*)d_in[0];
  const float* q_w    = (const float*)d_in[1];
  const float* q_b    = (const float*)d_in[2];
  const float* kv_w   = (const float*)d_in[3];
  const float* kv_b   = (const float*)d_in[4];
  const float* proj_w = (const float*)d_in[5];
  const float* proj_b = (const float*)d_in[6];
  float* out = (float*)d_out;

  // Workspace (offsets preserved).
  char* w = (char*)d_ws;
  float* xavg = (float*)w;                       // 4,718,592
  short* Xh   = (short*)(w + 4718592);
  short* Ah   = (short*)(w + 9437184);
  short* Wth  = (short*)(w + 28311552);          // 524,288 (hi only)
  short* Qhi  = (short*)(w + 29360128);          // 2,359,296
  short* Khi  = (short*)(w + 31719424);
  short* Vhi  = (short*)(w + 34078720);
  short* Zh   = (short*)(w + 37322752);          // 2,359,296

  const float qscale = 0.17677669529663689f * 1.4426950408889634f; // d^-0.5*log2(e)

  pool_kernel<<<BATCH * DIMC, 256, 0, stream>>>(x, xavg);
  conv_all<<<704, 256, 0, stream>>>(x, xavg, q_w, kv_w, proj_w, Xh, Ah, Wth);
  gemm_qkv_hi<<<dim3(36, 24, 2), 128, 0, stream>>>(Wth, q_b, kv_b,
                                                   Xh, Ah, Qhi, Khi, Vhi, qscale);
  attn_fused<<<2304, 256, 0, stream>>>(Qhi, Khi, Vhi, Zh);
  gemm_proj_hi<<<dim3(36, 8, 2), 128, 0, stream>>>(Wth + 196608, proj_b, Zh, out);
}

// Round 9
// 142.413 us; speedup vs baseline: 1.1810x; 1.1810x over previous
//
#include <hip/hip_runtime.h>
#include <hip/hip_bf16.h>
#include <cstdint>

// Problem constants
#define DIMC  256
#define NH    8
#define HD    32
#define NPIX  2304       // 48*48
#define BATCH 2
#define KT    32
#define NWAVE 4          // waves per attn block
#define NTW   18         // k-tiles per wave (72 tiles / 4 waves)
#define KPW   576        // keys per wave (NTW*KT)

typedef short s16x8 __attribute__((ext_vector_type(8)));
typedef short s16x4 __attribute__((ext_vector_type(4)));
typedef float f32x4 __attribute__((ext_vector_type(4)));

#define MFMA32(A,B,C) __builtin_amdgcn_mfma_f32_16x16x32_bf16(A,B,C,0,0,0)

// RNA (round-to-nearest-away) bf16 helpers: 1 VALU each.
__device__ inline uint32_t rnau(float x) { return __float_as_uint(x) + 0x8000u; }
__device__ inline uint32_t pk2(uint32_t l_, uint32_t h_) {
  return __builtin_amdgcn_perm(h_, l_, 0x07060302u);  // lo short=l_, hi short=h_
}

// ---------------------------------------------------------------------------
// Pool: x_avg = (x + box3/9 + box5/25 + box7/49)/4, zero-pad, include_pad
// ---------------------------------------------------------------------------
__global__ __launch_bounds__(256) void pool_kernel(const float* __restrict__ x,
                                                   float* __restrict__ xavg) {
  const int plane = blockIdx.x;
  const float* xp = x + (size_t)plane * NPIX;
  __shared__ float sx[NPIX];
  __shared__ float h3[NPIX], h5[NPIX], h7[NPIX];
  const int t = threadIdx.x;
#pragma unroll
  for (int r = 0; r < 9; ++r) sx[r * 256 + t] = xp[r * 256 + t];
  __syncthreads();
#pragma unroll
  for (int r = 0; r < 9; ++r) {
    int p = r * 256 + t;
    int i = p / 48, j = p - i * 48;
    float a3 = 0.f, a5 = 0.f, a7 = 0.f;
#pragma unroll
    for (int dj = -3; dj <= 3; ++dj) {
      int jj = j + dj;
      if (jj < 0 || jj >= 48) continue;
      float v = sx[i * 48 + jj];
      a7 += v;
      if (dj >= -2 && dj <= 2) a5 += v;
      if (dj >= -1 && dj <= 1) a3 += v;
    }
    h3[p] = a3; h5[p] = a5; h7[p] = a7;
  }
  __syncthreads();
#pragma unroll
  for (int r = 0; r < 9; ++r) {
    int p = r * 256 + t;
    int i = p / 48, j = p - i * 48;
    float b3 = 0.f, b5 = 0.f, b7 = 0.f;
#pragma unroll
    for (int di = -3; di <= 3; ++di) {
      int ii = i + di;
      if (ii < 0 || ii >= 48) continue;
      int q = ii * 48 + j;
      b7 += h7[q];
      if (di >= -2 && di <= 2) b5 += h5[q];
      if (di >= -1 && di <= 1) b3 += h3[q];
    }
    xavg[(size_t)plane * NPIX + p] =
        0.25f * (sx[p] + b3 * (1.f / 9.f) + b5 * (1.f / 25.f) + b7 * (1.f / 49.f));
  }
}

// ---------------------------------------------------------------------------
// Fused converts: blocks 0..287 tconv(x), 288..575 tconv(xavg), 576..703 wconv
// All HI-ONLY. UNCHANGED.
// ---------------------------------------------------------------------------
__global__ __launch_bounds__(256) void conv_all(
    const float* __restrict__ x, const float* __restrict__ xavg,
    const float* __restrict__ qw, const float* __restrict__ kvw,
    const float* __restrict__ pw_,
    short* __restrict__ Xh, short* __restrict__ Ah,
    short* __restrict__ Wth) {
  const int bx = blockIdx.x;
  const int t = threadIdx.x;
  if (bx < 576) {
    const float* src = (bx < 288) ? x : xavg;
    short* dhi = (bx < 288) ? Xh : Ah;
    const int bb = (bx < 288) ? bx : bx - 288;
    const int n0 = (bb % 36) * 64, c0 = ((bb / 36) & 3) * 64, b = bb / 144;
    __shared__ __align__(16) float T[64][68];
    {
      const int c = t >> 2, n4 = (t & 3) * 16;
      const float* sp = src + ((size_t)b * DIMC + c0 + c) * NPIX + n0 + n4;
#pragma unroll
      for (int i2 = 0; i2 < 4; ++i2)
        *(f32x4*)&T[c][n4 + i2 * 4] = *(const f32x4*)(sp + i2 * 4);
    }
    __syncthreads();
    {
      const int n = t >> 2, c4 = (t & 3) * 16;
      float v[16];
#pragma unroll
      for (int i = 0; i < 16; ++i) v[i] = T[c4 + i][n];
      uint32_t a[16];
#pragma unroll
      for (int i = 0; i < 16; ++i) a[i] = rnau(v[i]);
      union { s16x8 s; uint32_t u[4]; } H0, H1;
#pragma unroll
      for (int j = 0; j < 4; ++j) {
        H0.u[j] = pk2(a[2 * j], a[2 * j + 1]);
        H1.u[j] = pk2(a[8 + 2 * j], a[8 + 2 * j + 1]);
      }
      const size_t off = ((size_t)b * NPIX + n0 + n) * DIMC + c0 + c4;
      *(s16x8*)(dhi + off) = H0.s; *(s16x8*)(dhi + off + 8) = H1.s;
    }
  } else {
    const int idx = ((bx - 576) * 256 + t) * 8;
    const float* s;
    int off;
    if (idx < 65536)       { s = qw;  off = idx; }
    else if (idx < 196608) { s = kvw; off = idx - 65536; }
    else                   { s = pw_; off = idx - 196608; }
    f32x4 x0 = *(const f32x4*)(s + off);
    f32x4 x1 = *(const f32x4*)(s + off + 4);
    float v[8] = {x0[0], x0[1], x0[2], x0[3], x1[0], x1[1], x1[2], x1[3]};
    uint32_t a[8];
#pragma unroll
    for (int i = 0; i < 8; ++i) a[i] = rnau(v[i]);
    union { s16x8 s; uint32_t u[4]; } H;
#pragma unroll
    for (int j = 0; j < 4; ++j) H.u[j] = pk2(a[2 * j], a[2 * j + 1]);
    *(s16x8*)(Wth + idx) = H.s;
  }
}

// ---------------------------------------------------------------------------
// QKV GEMM, WIDENED: 64 output channels per block (was 32) -> input tile
// re-read halved (Xh 4x, Ah 8x; was 8x/16x) and 2 MFMA per B-fragment load.
// by 0..3 = Q (o0=by*64), by 4..11 = KV (o0=(by-4)*64; 0..255 K, 256..511 V).
// V epilogue keeps the R6 mu-permutation (in-register P in attn).
// Per-output math order identical to R6 -> bitwise identical results.
// ---------------------------------------------------------------------------
__global__ __launch_bounds__(128) void gemm_qkv_hi(
    const short* __restrict__ Wth,
    const float* __restrict__ q_b, const float* __restrict__ kv_b,
    const short* __restrict__ Xh, const short* __restrict__ Ah,
    short* __restrict__ Qhi, short* __restrict__ Khi, short* __restrict__ Vhi,
    float qscale) {
  __shared__ __align__(16) float Cl[64][68];
  const int by = blockIdx.y;           // 0..11
  const bool isQ = (by < 4);
  const int o0 = isQ ? by * 64 : (by - 4) * 64;   // local Q- or KV-space
  const short* Wh = isQ ? Wth : Wth + 65536;
  const float* bias = isQ ? q_b : kv_b;
  const short* Inh = isQ ? Xh : Ah;
  const float scale = isQ ? qscale : 1.0f;
  short* d1 = isQ ? Qhi : Khi;         // used for Q/K epilogue
  const int n0 = blockIdx.x * 64;
  const int b  = blockIdx.z;

  const int tid = threadIdx.x;
  const int wave = tid >> 6, lane = tid & 63;
  const int g = lane >> 4, q = lane & 15;

  const short* wph = Wh + ((o0 + wave * 32 + q) * DIMC + g * 8);
  const short* iph = Inh + ((size_t)(b * NPIX + n0 + q) * DIMC + g * 8);

  f32x4 acc[2][4] = {{{0,0,0,0},{0,0,0,0},{0,0,0,0},{0,0,0,0}},
                     {{0,0,0,0},{0,0,0,0},{0,0,0,0},{0,0,0,0}}};
#pragma unroll
  for (int c0 = 0; c0 < DIMC; c0 += 32) {
    s16x8 a0 = *(const s16x8*)(wph + c0);
    s16x8 a1 = *(const s16x8*)(wph + 16 * DIMC + c0);
#pragma unroll
    for (int st = 0; st < 4; ++st) {
      s16x8 bh_ = *(const s16x8*)(iph + (size_t)st * 16 * DIMC + c0);
      acc[0][st] = MFMA32(a0, bh_, acc[0][st]);
      acc[1][st] = MFMA32(a1, bh_, acc[1][st]);
    }
  }
#pragma unroll
  for (int a16 = 0; a16 < 2; ++a16)
#pragma unroll
    for (int st = 0; st < 4; ++st)
#pragma unroll
      for (int r = 0; r < 4; ++r)
        Cl[wave * 32 + a16 * 16 + g * 4 + r][st * 16 + q] = acc[a16][st][r];
  __syncthreads();

  if (by < 8) {
    // Q or K: (C+bias)*scale, hi-only, layout [bh][n][32]; 64 channels.
    const int n = tid >> 1, oq = tid & 1;
#pragma unroll
    for (int h2 = 0; h2 < 2; ++h2) {
      const int h = (o0 >> 5) + h2;
      const float* bp = bias + o0 + h2 * 32 + oq * 16;
      float v[16];
#pragma unroll
      for (int i = 0; i < 16; ++i)
        v[i] = (Cl[h2 * 32 + oq * 16 + i][n] + bp[i]) * scale;
      uint32_t a[16];
#pragma unroll
      for (int i = 0; i < 16; ++i) a[i] = rnau(v[i]);
      union { s16x8 s; uint32_t u[4]; } H0, H1;
#pragma unroll
      for (int j = 0; j < 4; ++j) {
        H0.u[j] = pk2(a[2 * j], a[2 * j + 1]);
        H1.u[j] = pk2(a[8 + 2 * j], a[8 + 2 * j + 1]);
      }
      const size_t off = ((size_t)((b * 8 + h) * NPIX + n0 + n)) * HD + oq * 16;
      *(s16x8*)(d1 + off) = H0.s; *(s16x8*)(d1 + off + 8) = H1.s;
    }
  } else {
    // V hi-only: dst [bh][d][n], n mu-permuted within each 32-tile; 64 ch.
    const int o = tid >> 2, nc = (tid & 3) * 16;
#pragma unroll
    for (int h2 = 0; h2 < 2; ++h2) {
      const int ch = o0 + h2 * 32 + o;          // 256..511 in KV space
      const int h = (ch - 256) >> 5;
      const float bv = bias[ch];
      float v[16];
#pragma unroll
      for (int i2 = 0; i2 < 4; ++i2) {
        f32x4 t4 = *(const f32x4*)&Cl[h2 * 32 + o][nc + i2 * 4];
        v[i2 * 4 + 0] = t4[0] + bv; v[i2 * 4 + 1] = t4[1] + bv;
        v[i2 * 4 + 2] = t4[2] + bv; v[i2 * 4 + 3] = t4[3] + bv;
      }
      uint32_t a[16];
#pragma unroll
      for (int i = 0; i < 16; ++i) a[i] = rnau(v[i]);
      short* po = Vhi + ((size_t)((b * 8 + h) * HD + o)) * NPIX + n0 + (nc & 32);
      const int phase = (nc & 16) ? 4 : 0;
#pragma unroll
      for (int j = 0; j < 4; ++j) {
        uint2 wv;
        wv.x = pk2(a[4 * j], a[4 * j + 1]);
        wv.y = pk2(a[4 * j + 2], a[4 * j + 3]);
        *(uint2*)(po + phase + 8 * j) = wv;
      }
    }
  }
}

// ---------------------------------------------------------------------------
// MFMA flash attention — R6 VERBATIM (best measured: 43.0 us).
// 32 q-rows/block, 4-wave intra-block split-K, in-register P via
// mu-permuted V, XCD swizzle, LDS only for final reduction.
// ---------------------------------------------------------------------------
__global__ __launch_bounds__(256) void attn_fused(
    const short* __restrict__ Qhi,   // [bh][n][32]
    const short* __restrict__ Khi,   // [bh][n][32]
    const short* __restrict__ Vhi,   // [bh][32][N] (n mu-permuted per 32-tile)
    short* __restrict__ zh) {        // [b][pix][256] scrambled
  const int li = blockIdx.x;         // 0..1151
  const int r144 = li >> 3;          // 0..143
  const int bh = 2 * (li & 7) + (r144 >= 72 ? 1 : 0);
  const int qb = (r144 >= 72) ? r144 - 72 : r144;  // 32-row q block
  const int tid = threadIdx.x;
  const int wave = tid >> 6, lane = tid & 63;
  const int g = lane >> 4, q = lane & 15;
  const int base = qb * 32;

  // LDS: final reduction only. [4 waves][64 lanes][20 f32] = 20480 B.
  __shared__ __align__(16) float R[4][64][20];

  const size_t qoff = ((size_t)bh * NPIX + base + q) * HD + g * 8;
  const s16x8 qhA = *(const s16x8*)(Qhi + qoff);
  const s16x8 qhB = *(const s16x8*)(Qhi + qoff + 16 * HD);

  const short* kp = Khi + ((size_t)bh * NPIX + wave * KPW + q) * HD + g * 8;
  const short* vp = Vhi + ((size_t)bh * HD + q) * NPIX + wave * KPW + g * 8;

  const f32x4 Z4 = {0.f, 0.f, 0.f, 0.f};
  f32x4 OA0 = Z4, OA1 = Z4, OB0 = Z4, OB1 = Z4;
  f32x4 LA = Z4, LB = Z4;
  s16x8 kb[3][2], vb[3][2], pfA, pfB, vp0, vp1;

  union { s16x8 s; uint32_t u[4]; } ONE, ZZ;
  ONE.u[0] = 0x3F803F80u; ONE.u[1] = 0x3F803F80u;
  ONE.u[2] = 0x3F803F80u; ONE.u[3] = 0x3F803F80u;
  ZZ.u[0] = 0; ZZ.u[1] = 0; ZZ.u[2] = 0; ZZ.u[3] = 0;
  const s16x8 ones = ONE.s;
  pfA = ZZ.s; pfB = ZZ.s;          // P=0 -> first O/L MFMAs add exact 0
  vp0 = ones; vp1 = ones;          // finite (avoid NaN*0)

  kb[0][0] = *(const s16x8*)(kp);
  kb[0][1] = *(const s16x8*)(kp + 16 * HD);
  vb[0][0] = *(const s16x8*)(vp);
  vb[0][1] = *(const s16x8*)(vp + 16 * NPIX);
  kb[1][0] = *(const s16x8*)(kp + KT * HD);
  kb[1][1] = *(const s16x8*)(kp + KT * HD + 16 * HD);
  vb[1][0] = *(const s16x8*)(vp + KT);
  vb[1][1] = *(const s16x8*)(vp + KT + 16 * NPIX);

#define ATTN_STEP(CUR, NX2, T)                                                \
  {                                                                           \
    if ((T) + 2 < NTW) {                                                      \
      const short* kpn = kp + ((T) + 2) * (KT * HD);                          \
      const short* vpn = vp + ((T) + 2) * KT;                                 \
      kb[NX2][0] = *(const s16x8*)(kpn);                                      \
      kb[NX2][1] = *(const s16x8*)(kpn + 16 * HD);                            \
      vb[NX2][0] = *(const s16x8*)(vpn);                                      \
      vb[NX2][1] = *(const s16x8*)(vpn + 16 * NPIX);                          \
    }                                                                         \
    f32x4 SA0 = MFMA32(kb[CUR][0], qhA, Z4);                                  \
    f32x4 SA1 = MFMA32(kb[CUR][1], qhA, Z4);                                  \
    f32x4 SB0 = MFMA32(kb[CUR][0], qhB, Z4);                                  \
    f32x4 SB1 = MFMA32(kb[CUR][1], qhB, Z4);                                  \
    OA0 = MFMA32(vp0, pfA, OA0);                                              \
    OA1 = MFMA32(vp1, pfA, OA1);                                              \
    OB0 = MFMA32(vp0, pfB, OB0);                                              \
    OB1 = MFMA32(vp1, pfB, OB1);                                              \
    LA  = MFMA32(ones, pfA, LA);                                              \
    LB  = MFMA32(ones, pfB, LB);                                              \
    {                                                                         \
      f32x4 p0, p1;                                                           \
      p0[0] = exp2f(SA0[0]); p0[1] = exp2f(SA0[1]);                           \
      p0[2] = exp2f(SA0[2]); p0[3] = exp2f(SA0[3]);                           \
      p1[0] = exp2f(SA1[0]); p1[1] = exp2f(SA1[1]);                           \
      p1[2] = exp2f(SA1[2]); p1[3] = exp2f(SA1[3]);                           \
      union { s16x8 s; uint32_t u[4]; } PA;                                   \
      PA.u[0] = pk2(rnau(p0[0]), rnau(p0[1]));                                \
      PA.u[1] = pk2(rnau(p0[2]), rnau(p0[3]));                                \
      PA.u[2] = pk2(rnau(p1[0]), rnau(p1[1]));                                \
      PA.u[3] = pk2(rnau(p1[2]), rnau(p1[3]));                                \
      pfA = PA.s;                                                             \
    }                                                                         \
    {                                                                         \
      f32x4 p0, p1;                                                           \
      p0[0] = exp2f(SB0[0]); p0[1] = exp2f(SB0[1]);                           \
      p0[2] = exp2f(SB0[2]); p0[3] = exp2f(SB0[3]);                           \
      p1[0] = exp2f(SB1[0]); p1[1] = exp2f(SB1[1]);                           \
      p1[2] = exp2f(SB1[2]); p1[3] = exp2f(SB1[3]);                           \
      union { s16x8 s; uint32_t u[4]; } PB;                                   \
      PB.u[0] = pk2(rnau(p0[0]), rnau(p0[1]));                                \
      PB.u[1] = pk2(rnau(p0[2]), rnau(p0[3]));                                \
      PB.u[2] = pk2(rnau(p1[0]), rnau(p1[1]));                                \
      PB.u[3] = pk2(rnau(p1[2]), rnau(p1[3]));                                \
      pfB = PB.s;                                                             \
    }                                                                         \
    vp0 = vb[CUR][0]; vp1 = vb[CUR][1];                                       \
  }

#pragma unroll 1
  for (int tt = 0; tt < NTW; tt += 3) {
    ATTN_STEP(0, 2, tt);
    ATTN_STEP(1, 0, tt + 1);
    ATTN_STEP(2, 1, tt + 2);
  }
#undef ATTN_STEP

  // Tail: consume P of the wave's last tile
  OA0 = MFMA32(vp0, pfA, OA0);
  OA1 = MFMA32(vp1, pfA, OA1);
  OB0 = MFMA32(vp0, pfB, OB0);
  OB1 = MFMA32(vp1, pfB, OB1);
  LA  = MFMA32(ones, pfA, LA);
  LB  = MFMA32(ones, pfB, LB);

  {
    float* rw = &R[wave][lane][0];
    *(f32x4*)&rw[0]  = OA0;   // d = g*4+r        (rows nA)
    *(f32x4*)&rw[4]  = OA1;   // d = 16+g*4+r
    *(f32x4*)&rw[8]  = OB0;   // d = g*4+r        (rows nB)
    *(f32x4*)&rw[12] = OB1;   // d = 16+g*4+r
    rw[16] = LA[0];           // L rows identical -> LA[0] = L[q-row A]
    rw[17] = LB[0];
  }
  __syncthreads();
  {
    // 256 threads: lane-slot l2, element group eg (4 O-elems each).
    const int l2 = tid & 63, eg = tid >> 6;
    const int g2 = l2 >> 4, q2 = l2 & 15;
    f32x4 s = {0.f, 0.f, 0.f, 0.f};
    float Lt = 0.f;
#pragma unroll
    for (int w = 0; w < NWAVE; ++w) {
      const f32x4 pv = *(const f32x4*)&R[w][l2][eg * 4];
      s[0] += pv[0]; s[1] += pv[1]; s[2] += pv[2]; s[3] += pv[3];
      Lt += R[w][l2][16 + (eg >> 1)];
    }
    const float inv = 1.f / Lt;
    const int h = bh & 7, b = bh >> 3;
    const int n = base + ((eg & 2) ? 16 : 0) + q2;
    const int d0 = ((eg & 1) ? 16 : 0) + g2 * 4;
    const int c = n / 9, r = n - c * 9;
    short* zp = zh + ((size_t)(b * NPIX + r * 256 + h * HD + d0)) * DIMC + c;
#pragma unroll
    for (int j = 0; j < 4; ++j)
      zp[(size_t)j * DIMC] = (short)(rnau(s[j] * inv) >> 16);
  }
}

// ---------------------------------------------------------------------------
// PROJ GEMM, WIDENED: 64 output channels per block (was 32) -> Zh re-read
// halved (4x, was 8x), 2 MFMA per B-fragment. Bitwise-identical outputs.
// ---------------------------------------------------------------------------
__global__ __launch_bounds__(128) void gemm_proj_hi(
    const short* __restrict__ Wh,
    const float* __restrict__ bias,
    const short* __restrict__ Zh,
    float* __restrict__ out) {
  __shared__ __align__(16) float Cl[64][68];
  const int n0 = blockIdx.x * 64;
  const int o0 = blockIdx.y * 64;
  const int b  = blockIdx.z;
  const int tid = threadIdx.x;
  const int wave = tid >> 6, lane = tid & 63;
  const int g = lane >> 4, q = lane & 15;

  const short* wph = Wh + ((o0 + wave * 32 + q) * DIMC + g * 8);
  const short* iph = Zh + ((size_t)(b * NPIX + n0 + q) * DIMC + g * 8);

  f32x4 acc[2][4] = {{{0,0,0,0},{0,0,0,0},{0,0,0,0},{0,0,0,0}},
                     {{0,0,0,0},{0,0,0,0},{0,0,0,0},{0,0,0,0}}};
#pragma unroll
  for (int c0 = 0; c0 < DIMC; c0 += 32) {
    s16x8 a0 = *(const s16x8*)(wph + c0);
    s16x8 a1 = *(const s16x8*)(wph + 16 * DIMC + c0);
#pragma unroll
    for (int st = 0; st < 4; ++st) {
      s16x8 bh_ = *(const s16x8*)(iph + (size_t)st * 16 * DIMC + c0);
      acc[0][st] = MFMA32(a0, bh_, acc[0][st]);
      acc[1][st] = MFMA32(a1, bh_, acc[1][st]);
    }
  }
#pragma unroll
  for (int a16 = 0; a16 < 2; ++a16)
#pragma unroll
    for (int st = 0; st < 4; ++st)
#pragma unroll
      for (int r = 0; r < 4; ++r)
        Cl[wave * 32 + a16 * 16 + g * 4 + r][st * 16 + q] = acc[a16][st][r];
  __syncthreads();

  const int o = tid >> 2, nc = (tid & 3) * 16;
#pragma unroll
  for (int h2 = 0; h2 < 2; ++h2) {
    const int row = h2 * 32 + o;
    const float bv = bias[o0 + row];
    float* op = out + ((size_t)b * DIMC + o0 + row) * NPIX + n0 + nc;
#pragma unroll
    for (int i2 = 0; i2 < 4; ++i2) {
      f32x4 v = *(const f32x4*)&Cl[row][nc + i2 * 4];
      v[0] += bv; v[1] += bv; v[2] += bv; v[3] += bv;
      *(f32x4*)(op + i2 * 4) = v;
    }
  }
}

// ---------------------------------------------------------------------------
extern "C" void kernel_launch(void* const* d_in, const int* in_sizes, int n_in,
                              void* d_out, int out_size, void* d_ws, size_t ws_size,
                              hipStream_t stream) {
  const float* x      = (const float*)d_in[0];
  const float* q_w    = (const float*)d_in[1];
  const float* q_b    = (const float*)d_in[2];
  const float* kv_w   = (const float*)d_in[3];
  const float* kv_b   = (const float*)d_in[4];
  const float* proj_w = (const float*)d_in[5];
  const float* proj_b = (const float*)d_in[6];
  float* out = (float*)d_out;

  // Workspace (offsets preserved).
  char* w = (char*)d_ws;
  float* xavg = (float*)w;                       // 4,718,592
  short* Xh   = (short*)(w + 4718592);
  short* Ah   = (short*)(w + 9437184);
  short* Wth  = (short*)(w + 28311552);          // 524,288 (hi only)
  short* Qhi  = (short*)(w + 29360128);          // 2,359,296
  short* Khi  = (short*)(w + 31719424);
  short* Vhi  = (short*)(w + 34078720);
  short* Zh   = (short*)(w + 37322752);          // 2,359,296

  const float qscale = 0.17677669529663689f * 1.4426950408889634f; // d^-0.5*log2(e)

  pool_kernel<<<BATCH * DIMC, 256, 0, stream>>>(x, xavg);
  conv_all<<<704, 256, 0, stream>>>(x, xavg, q_w, kv_w, proj_w, Xh, Ah, Wth);
  gemm_qkv_hi<<<dim3(36, 12, 2), 128, 0, stream>>>(Wth, q_b, kv_b,
                                                   Xh, Ah, Qhi, Khi, Vhi, qscale);
  attn_fused<<<1152, 256, 0, stream>>>(Qhi, Khi, Vhi, Zh);
  gemm_proj_hi<<<dim3(36, 4, 2), 128, 0, stream>>>(Wth + 196608, proj_b, Zh, out);
}

// Round 10
// 141.763 us; speedup vs baseline: 1.1864x; 1.0046x over previous
//
#include <hip/hip_runtime.h>
#include <hip/hip_bf16.h>
#include <cstdint>

// Problem constants
#define DIMC  256
#define NH    8
#define HD    32
#define NPIX  2304       // 48*48
#define BATCH 2
#define KT    32
#define NWAVE 4          // waves per attn block
#define NTW   18         // k-tiles per wave (72 tiles / 4 waves)
#define KPW   576        // keys per wave (NTW*KT)

typedef short s16x8 __attribute__((ext_vector_type(8)));
typedef short s16x4 __attribute__((ext_vector_type(4)));
typedef float f32x4 __attribute__((ext_vector_type(4)));

#define MFMA32(A,B,C) __builtin_amdgcn_mfma_f32_16x16x32_bf16(A,B,C,0,0,0)

// RNA (round-to-nearest-away) bf16 helpers: 1 VALU each.
__device__ inline uint32_t rnau(float x) { return __float_as_uint(x) + 0x8000u; }
__device__ inline uint32_t pk2(uint32_t l_, uint32_t h_) {
  return __builtin_amdgcn_perm(h_, l_, 0x07060302u);  // lo short=l_, hi short=h_
}
// HW packed f32x2 -> bf16x2 (RNE), 1 VALU op (T12 primitive).
__device__ inline uint32_t cvtpk(float lo, float hi) {
  uint32_t r;
  asm("v_cvt_pk_bf16_f32 %0, %1, %2" : "=v"(r) : "v"(lo), "v"(hi));
  return r;
}

// ---------------------------------------------------------------------------
// Pool: x_avg = (x + box3/9 + box5/25 + box7/49)/4, zero-pad, include_pad
// ---------------------------------------------------------------------------
__global__ __launch_bounds__(256) void pool_kernel(const float* __restrict__ x,
                                                   float* __restrict__ xavg) {
  const int plane = blockIdx.x;
  const float* xp = x + (size_t)plane * NPIX;
  __shared__ float sx[NPIX];
  __shared__ float h3[NPIX], h5[NPIX], h7[NPIX];
  const int t = threadIdx.x;
#pragma unroll
  for (int r = 0; r < 9; ++r) sx[r * 256 + t] = xp[r * 256 + t];
  __syncthreads();
#pragma unroll
  for (int r = 0; r < 9; ++r) {
    int p = r * 256 + t;
    int i = p / 48, j = p - i * 48;
    float a3 = 0.f, a5 = 0.f, a7 = 0.f;
#pragma unroll
    for (int dj = -3; dj <= 3; ++dj) {
      int jj = j + dj;
      if (jj < 0 || jj >= 48) continue;
      float v = sx[i * 48 + jj];
      a7 += v;
      if (dj >= -2 && dj <= 2) a5 += v;
      if (dj >= -1 && dj <= 1) a3 += v;
    }
    h3[p] = a3; h5[p] = a5; h7[p] = a7;
  }
  __syncthreads();
#pragma unroll
  for (int r = 0; r < 9; ++r) {
    int p = r * 256 + t;
    int i = p / 48, j = p - i * 48;
    float b3 = 0.f, b5 = 0.f, b7 = 0.f;
#pragma unroll
    for (int di = -3; di <= 3; ++di) {
      int ii = i + di;
      if (ii < 0 || ii >= 48) continue;
      int q = ii * 48 + j;
      b7 += h7[q];
      if (di >= -2 && di <= 2) b5 += h5[q];
      if (di >= -1 && di <= 1) b3 += h3[q];
    }
    xavg[(size_t)plane * NPIX + p] =
        0.25f * (sx[p] + b3 * (1.f / 9.f) + b5 * (1.f / 25.f) + b7 * (1.f / 49.f));
  }
}

// ---------------------------------------------------------------------------
// Fused converts: blocks 0..287 tconv(x), 288..575 tconv(xavg), 576..703 wconv
// All HI-ONLY. UNCHANGED.
// ---------------------------------------------------------------------------
__global__ __launch_bounds__(256) void conv_all(
    const float* __restrict__ x, const float* __restrict__ xavg,
    const float* __restrict__ qw, const float* __restrict__ kvw,
    const float* __restrict__ pw_,
    short* __restrict__ Xh, short* __restrict__ Ah,
    short* __restrict__ Wth) {
  const int bx = blockIdx.x;
  const int t = threadIdx.x;
  if (bx < 576) {
    const float* src = (bx < 288) ? x : xavg;
    short* dhi = (bx < 288) ? Xh : Ah;
    const int bb = (bx < 288) ? bx : bx - 288;
    const int n0 = (bb % 36) * 64, c0 = ((bb / 36) & 3) * 64, b = bb / 144;
    __shared__ __align__(16) float T[64][68];
    {
      const int c = t >> 2, n4 = (t & 3) * 16;
      const float* sp = src + ((size_t)b * DIMC + c0 + c) * NPIX + n0 + n4;
#pragma unroll
      for (int i2 = 0; i2 < 4; ++i2)
        *(f32x4*)&T[c][n4 + i2 * 4] = *(const f32x4*)(sp + i2 * 4);
    }
    __syncthreads();
    {
      const int n = t >> 2, c4 = (t & 3) * 16;
      float v[16];
#pragma unroll
      for (int i = 0; i < 16; ++i) v[i] = T[c4 + i][n];
      uint32_t a[16];
#pragma unroll
      for (int i = 0; i < 16; ++i) a[i] = rnau(v[i]);
      union { s16x8 s; uint32_t u[4]; } H0, H1;
#pragma unroll
      for (int j = 0; j < 4; ++j) {
        H0.u[j] = pk2(a[2 * j], a[2 * j + 1]);
        H1.u[j] = pk2(a[8 + 2 * j], a[8 + 2 * j + 1]);
      }
      const size_t off = ((size_t)b * NPIX + n0 + n) * DIMC + c0 + c4;
      *(s16x8*)(dhi + off) = H0.s; *(s16x8*)(dhi + off + 8) = H1.s;
    }
  } else {
    const int idx = ((bx - 576) * 256 + t) * 8;
    const float* s;
    int off;
    if (idx < 65536)       { s = qw;  off = idx; }
    else if (idx < 196608) { s = kvw; off = idx - 65536; }
    else                   { s = pw_; off = idx - 196608; }
    f32x4 x0 = *(const f32x4*)(s + off);
    f32x4 x1 = *(const f32x4*)(s + off + 4);
    float v[8] = {x0[0], x0[1], x0[2], x0[3], x1[0], x1[1], x1[2], x1[3]};
    uint32_t a[8];
#pragma unroll
    for (int i = 0; i < 8; ++i) a[i] = rnau(v[i]);
    union { s16x8 s; uint32_t u[4]; } H;
#pragma unroll
    for (int j = 0; j < 4; ++j) H.u[j] = pk2(a[2 * j], a[2 * j + 1]);
    *(s16x8*)(Wth + idx) = H.s;
  }
}

// ---------------------------------------------------------------------------
// QKV GEMM, WIDENED (R8): 64 output channels per block. V epilogue keeps the
// R6 mu-permutation. Bitwise-identical outputs to R6.
// ---------------------------------------------------------------------------
__global__ __launch_bounds__(128) void gemm_qkv_hi(
    const short* __restrict__ Wth,
    const float* __restrict__ q_b, const float* __restrict__ kv_b,
    const short* __restrict__ Xh, const short* __restrict__ Ah,
    short* __restrict__ Qhi, short* __restrict__ Khi, short* __restrict__ Vhi,
    float qscale) {
  __shared__ __align__(16) float Cl[64][68];
  const int by = blockIdx.y;           // 0..11
  const bool isQ = (by < 4);
  const int o0 = isQ ? by * 64 : (by - 4) * 64;   // local Q- or KV-space
  const short* Wh = isQ ? Wth : Wth + 65536;
  const float* bias = isQ ? q_b : kv_b;
  const short* Inh = isQ ? Xh : Ah;
  const float scale = isQ ? qscale : 1.0f;
  short* d1 = isQ ? Qhi : Khi;         // used for Q/K epilogue
  const int n0 = blockIdx.x * 64;
  const int b  = blockIdx.z;

  const int tid = threadIdx.x;
  const int wave = tid >> 6, lane = tid & 63;
  const int g = lane >> 4, q = lane & 15;

  const short* wph = Wh + ((o0 + wave * 32 + q) * DIMC + g * 8);
  const short* iph = Inh + ((size_t)(b * NPIX + n0 + q) * DIMC + g * 8);

  f32x4 acc[2][4] = {{{0,0,0,0},{0,0,0,0},{0,0,0,0},{0,0,0,0}},
                     {{0,0,0,0},{0,0,0,0},{0,0,0,0},{0,0,0,0}}};
#pragma unroll
  for (int c0 = 0; c0 < DIMC; c0 += 32) {
    s16x8 a0 = *(const s16x8*)(wph + c0);
    s16x8 a1 = *(const s16x8*)(wph + 16 * DIMC + c0);
#pragma unroll
    for (int st = 0; st < 4; ++st) {
      s16x8 bh_ = *(const s16x8*)(iph + (size_t)st * 16 * DIMC + c0);
      acc[0][st] = MFMA32(a0, bh_, acc[0][st]);
      acc[1][st] = MFMA32(a1, bh_, acc[1][st]);
    }
  }
#pragma unroll
  for (int a16 = 0; a16 < 2; ++a16)
#pragma unroll
    for (int st = 0; st < 4; ++st)
#pragma unroll
      for (int r = 0; r < 4; ++r)
        Cl[wave * 32 + a16 * 16 + g * 4 + r][st * 16 + q] = acc[a16][st][r];
  __syncthreads();

  if (by < 8) {
    // Q or K: (C+bias)*scale, hi-only, layout [bh][n][32]; 64 channels.
    const int n = tid >> 1, oq = tid & 1;
#pragma unroll
    for (int h2 = 0; h2 < 2; ++h2) {
      const int h = (o0 >> 5) + h2;
      const float* bp = bias + o0 + h2 * 32 + oq * 16;
      float v[16];
#pragma unroll
      for (int i = 0; i < 16; ++i)
        v[i] = (Cl[h2 * 32 + oq * 16 + i][n] + bp[i]) * scale;
      uint32_t a[16];
#pragma unroll
      for (int i = 0; i < 16; ++i) a[i] = rnau(v[i]);
      union { s16x8 s; uint32_t u[4]; } H0, H1;
#pragma unroll
      for (int j = 0; j < 4; ++j) {
        H0.u[j] = pk2(a[2 * j], a[2 * j + 1]);
        H1.u[j] = pk2(a[8 + 2 * j], a[8 + 2 * j + 1]);
      }
      const size_t off = ((size_t)((b * 8 + h) * NPIX + n0 + n)) * HD + oq * 16;
      *(s16x8*)(d1 + off) = H0.s; *(s16x8*)(d1 + off + 8) = H1.s;
    }
  } else {
    // V hi-only: dst [bh][d][n], n mu-permuted within each 32-tile; 64 ch.
    const int o = tid >> 2, nc = (tid & 3) * 16;
#pragma unroll
    for (int h2 = 0; h2 < 2; ++h2) {
      const int ch = o0 + h2 * 32 + o;          // 256..511 in KV space
      const int h = (ch - 256) >> 5;
      const float bv = bias[ch];
      float v[16];
#pragma unroll
      for (int i2 = 0; i2 < 4; ++i2) {
        f32x4 t4 = *(const f32x4*)&Cl[h2 * 32 + o][nc + i2 * 4];
        v[i2 * 4 + 0] = t4[0] + bv; v[i2 * 4 + 1] = t4[1] + bv;
        v[i2 * 4 + 2] = t4[2] + bv; v[i2 * 4 + 3] = t4[3] + bv;
      }
      uint32_t a[16];
#pragma unroll
      for (int i = 0; i < 16; ++i) a[i] = rnau(v[i]);
      short* po = Vhi + ((size_t)((b * 8 + h) * HD + o)) * NPIX + n0 + (nc & 32);
      const int phase = (nc & 16) ? 4 : 0;
#pragma unroll
      for (int j = 0; j < 4; ++j) {
        uint2 wv;
        wv.x = pk2(a[4 * j], a[4 * j + 1]);
        wv.y = pk2(a[4 * j + 2], a[4 * j + 3]);
        *(uint2*)(po + phase + 8 * j) = wv;
      }
    }
  }
}

// ---------------------------------------------------------------------------
// MFMA flash attention — R6/R8 structure; P-pack now via v_cvt_pk_bf16_f32
// (1 VALU per f32-pair vs 3 with rnau+pk2): per-step VALU issue −18%.
// Rounding on P changes RNA->RNE; O and L consume the SAME pf, so softmax
// errors stay correlated. Everything else unchanged.
// ---------------------------------------------------------------------------
__global__ __launch_bounds__(256) void attn_fused(
    const short* __restrict__ Qhi,   // [bh][n][32]
    const short* __restrict__ Khi,   // [bh][n][32]
    const short* __restrict__ Vhi,   // [bh][32][N] (n mu-permuted per 32-tile)
    short* __restrict__ zh) {        // [b][pix][256] scrambled
  const int li = blockIdx.x;         // 0..1151
  const int r144 = li >> 3;          // 0..143
  const int bh = 2 * (li & 7) + (r144 >= 72 ? 1 : 0);
  const int qb = (r144 >= 72) ? r144 - 72 : r144;  // 32-row q block
  const int tid = threadIdx.x;
  const int wave = tid >> 6, lane = tid & 63;
  const int g = lane >> 4, q = lane & 15;
  const int base = qb * 32;

  // LDS: final reduction only. [4 waves][64 lanes][20 f32] = 20480 B.
  __shared__ __align__(16) float R[4][64][20];

  const size_t qoff = ((size_t)bh * NPIX + base + q) * HD + g * 8;
  const s16x8 qhA = *(const s16x8*)(Qhi + qoff);
  const s16x8 qhB = *(const s16x8*)(Qhi + qoff + 16 * HD);

  const short* kp = Khi + ((size_t)bh * NPIX + wave * KPW + q) * HD + g * 8;
  const short* vp = Vhi + ((size_t)bh * HD + q) * NPIX + wave * KPW + g * 8;

  const f32x4 Z4 = {0.f, 0.f, 0.f, 0.f};
  f32x4 OA0 = Z4, OA1 = Z4, OB0 = Z4, OB1 = Z4;
  f32x4 LA = Z4, LB = Z4;
  s16x8 kb[3][2], vb[3][2], pfA, pfB, vp0, vp1;

  union { s16x8 s; uint32_t u[4]; } ONE, ZZ;
  ONE.u[0] = 0x3F803F80u; ONE.u[1] = 0x3F803F80u;
  ONE.u[2] = 0x3F803F80u; ONE.u[3] = 0x3F803F80u;
  ZZ.u[0] = 0; ZZ.u[1] = 0; ZZ.u[2] = 0; ZZ.u[3] = 0;
  const s16x8 ones = ONE.s;
  pfA = ZZ.s; pfB = ZZ.s;          // P=0 -> first O/L MFMAs add exact 0
  vp0 = ones; vp1 = ones;          // finite (avoid NaN*0)

  kb[0][0] = *(const s16x8*)(kp);
  kb[0][1] = *(const s16x8*)(kp + 16 * HD);
  vb[0][0] = *(const s16x8*)(vp);
  vb[0][1] = *(const s16x8*)(vp + 16 * NPIX);
  kb[1][0] = *(const s16x8*)(kp + KT * HD);
  kb[1][1] = *(const s16x8*)(kp + KT * HD + 16 * HD);
  vb[1][0] = *(const s16x8*)(vp + KT);
  vb[1][1] = *(const s16x8*)(vp + KT + 16 * NPIX);

#define ATTN_STEP(CUR, NX2, T)                                                \
  {                                                                           \
    if ((T) + 2 < NTW) {                                                      \
      const short* kpn = kp + ((T) + 2) * (KT * HD);                          \
      const short* vpn = vp + ((T) + 2) * KT;                                 \
      kb[NX2][0] = *(const s16x8*)(kpn);                                      \
      kb[NX2][1] = *(const s16x8*)(kpn + 16 * HD);                            \
      vb[NX2][0] = *(const s16x8*)(vpn);                                      \
      vb[NX2][1] = *(const s16x8*)(vpn + 16 * NPIX);                          \
    }                                                                         \
    f32x4 SA0 = MFMA32(kb[CUR][0], qhA, Z4);                                  \
    f32x4 SA1 = MFMA32(kb[CUR][1], qhA, Z4);                                  \
    f32x4 SB0 = MFMA32(kb[CUR][0], qhB, Z4);                                  \
    f32x4 SB1 = MFMA32(kb[CUR][1], qhB, Z4);                                  \
    OA0 = MFMA32(vp0, pfA, OA0);                                              \
    OA1 = MFMA32(vp1, pfA, OA1);                                              \
    OB0 = MFMA32(vp0, pfB, OB0);                                              \
    OB1 = MFMA32(vp1, pfB, OB1);                                              \
    LA  = MFMA32(ones, pfA, LA);                                              \
    LB  = MFMA32(ones, pfB, LB);                                              \
    {                                                                         \
      union { s16x8 s; uint32_t u[4]; } PA;                                   \
      PA.u[0] = cvtpk(exp2f(SA0[0]), exp2f(SA0[1]));                          \
      PA.u[1] = cvtpk(exp2f(SA0[2]), exp2f(SA0[3]));                          \
      PA.u[2] = cvtpk(exp2f(SA1[0]), exp2f(SA1[1]));                          \
      PA.u[3] = cvtpk(exp2f(SA1[2]), exp2f(SA1[3]));                          \
      pfA = PA.s;                                                             \
    }                                                                         \
    {                                                                         \
      union { s16x8 s; uint32_t u[4]; } PB;                                   \
      PB.u[0] = cvtpk(exp2f(SB0[0]), exp2f(SB0[1]));                          \
      PB.u[1] = cvtpk(exp2f(SB0[2]), exp2f(SB0[3]));                          \
      PB.u[2] = cvtpk(exp2f(SB1[0]), exp2f(SB1[1]));                          \
      PB.u[3] = cvtpk(exp2f(SB1[2]), exp2f(SB1[3]));                          \
      pfB = PB.s;                                                             \
    }                                                                         \
    vp0 = vb[CUR][0]; vp1 = vb[CUR][1];                                       \
  }

#pragma unroll 1
  for (int tt = 0; tt < NTW; tt += 3) {
    ATTN_STEP(0, 2, tt);
    ATTN_STEP(1, 0, tt + 1);
    ATTN_STEP(2, 1, tt + 2);
  }
#undef ATTN_STEP

  // Tail: consume P of the wave's last tile
  OA0 = MFMA32(vp0, pfA, OA0);
  OA1 = MFMA32(vp1, pfA, OA1);
  OB0 = MFMA32(vp0, pfB, OB0);
  OB1 = MFMA32(vp1, pfB, OB1);
  LA  = MFMA32(ones, pfA, LA);
  LB  = MFMA32(ones, pfB, LB);

  {
    float* rw = &R[wave][lane][0];
    *(f32x4*)&rw[0]  = OA0;   // d = g*4+r        (rows nA)
    *(f32x4*)&rw[4]  = OA1;   // d = 16+g*4+r
    *(f32x4*)&rw[8]  = OB0;   // d = g*4+r        (rows nB)
    *(f32x4*)&rw[12] = OB1;   // d = 16+g*4+r
    rw[16] = LA[0];           // L rows identical -> LA[0] = L[q-row A]
    rw[17] = LB[0];
  }
  __syncthreads();
  {
    // 256 threads: lane-slot l2, element group eg (4 O-elems each).
    const int l2 = tid & 63, eg = tid >> 6;
    const int g2 = l2 >> 4, q2 = l2 & 15;
    f32x4 s = {0.f, 0.f, 0.f, 0.f};
    float Lt = 0.f;
#pragma unroll
    for (int w = 0; w < NWAVE; ++w) {
      const f32x4 pv = *(const f32x4*)&R[w][l2][eg * 4];
      s[0] += pv[0]; s[1] += pv[1]; s[2] += pv[2]; s[3] += pv[3];
      Lt += R[w][l2][16 + (eg >> 1)];
    }
    const float inv = 1.f / Lt;
    const int h = bh & 7, b = bh >> 3;
    const int n = base + ((eg & 2) ? 16 : 0) + q2;
    const int d0 = ((eg & 1) ? 16 : 0) + g2 * 4;
    const int c = n / 9, r = n - c * 9;
    short* zp = zh + ((size_t)(b * NPIX + r * 256 + h * HD + d0)) * DIMC + c;
#pragma unroll
    for (int j = 0; j < 4; ++j)
      zp[(size_t)j * DIMC] = (short)(rnau(s[j] * inv) >> 16);
  }
}

// ---------------------------------------------------------------------------
// PROJ GEMM, WIDENED (R8): 64 output channels per block. UNCHANGED.
// ---------------------------------------------------------------------------
__global__ __launch_bounds__(128) void gemm_proj_hi(
    const short* __restrict__ Wh,
    const float* __restrict__ bias,
    const short* __restrict__ Zh,
    float* __restrict__ out) {
  __shared__ __align__(16) float Cl[64][68];
  const int n0 = blockIdx.x * 64;
  const int o0 = blockIdx.y * 64;
  const int b  = blockIdx.z;
  const int tid = threadIdx.x;
  const int wave = tid >> 6, lane = tid & 63;
  const int g = lane >> 4, q = lane & 15;

  const short* wph = Wh + ((o0 + wave * 32 + q) * DIMC + g * 8);
  const short* iph = Zh + ((size_t)(b * NPIX + n0 + q) * DIMC + g * 8);

  f32x4 acc[2][4] = {{{0,0,0,0},{0,0,0,0},{0,0,0,0},{0,0,0,0}},
                     {{0,0,0,0},{0,0,0,0},{0,0,0,0},{0,0,0,0}}};
#pragma unroll
  for (int c0 = 0; c0 < DIMC; c0 += 32) {
    s16x8 a0 = *(const s16x8*)(wph + c0);
    s16x8 a1 = *(const s16x8*)(wph + 16 * DIMC + c0);
#pragma unroll
    for (int st = 0; st < 4; ++st) {
      s16x8 bh_ = *(const s16x8*)(iph + (size_t)st * 16 * DIMC + c0);
      acc[0][st] = MFMA32(a0, bh_, acc[0][st]);
      acc[1][st] = MFMA32(a1, bh_, acc[1][st]);
    }
  }
#pragma unroll
  for (int a16 = 0; a16 < 2; ++a16)
#pragma unroll
    for (int st = 0; st < 4; ++st)
#pragma unroll
      for (int r = 0; r < 4; ++r)
        Cl[wave * 32 + a16 * 16 + g * 4 + r][st * 16 + q] = acc[a16][st][r];
  __syncthreads();

  const int o = tid >> 2, nc = (tid & 3) * 16;
#pragma unroll
  for (int h2 = 0; h2 < 2; ++h2) {
    const int row = h2 * 32 + o;
    const float bv = bias[o0 + row];
    float* op = out + ((size_t)b * DIMC + o0 + row) * NPIX + n0 + nc;
#pragma unroll
    for (int i2 = 0; i2 < 4; ++i2) {
      f32x4 v = *(const f32x4*)&Cl[row][nc + i2 * 4];
      v[0] += bv; v[1] += bv; v[2] += bv; v[3] += bv;
      *(f32x4*)(op + i2 * 4) = v;
    }
  }
}

// ---------------------------------------------------------------------------
extern "C" void kernel_launch(void* const* d_in, const int* in_sizes, int n_in,
                              void* d_out, int out_size, void* d_ws, size_t ws_size,
                              hipStream_t stream) {
  const float* x      = (const float*)d_in[0];
  const float* q_w    = (const float*)d_in[1];
  const float* q_b    = (const float*)d_in[2];
  const float* kv_w   = (const float*)d_in[3];
  const float* kv_b   = (const float*)d_in[4];
  const float* proj_w = (const float*)d_in[5];
  const float* proj_b = (const float*)d_in[6];
  float* out = (float*)d_out;

  // Workspace (offsets preserved).
  char* w = (char*)d_ws;
  float* xavg = (float*)w;                       // 4,718,592
  short* Xh   = (short*)(w + 4718592);
  short* Ah   = (short*)(w + 9437184);
  short* Wth  = (short*)(w + 28311552);          // 524,288 (hi only)
  short* Qhi  = (short*)(w + 29360128);          // 2,359,296
  short* Khi  = (short*)(w + 31719424);
  short* Vhi  = (short*)(w + 34078720);
  short* Zh   = (short*)(w + 37322752);          // 2,359,296

  const float qscale = 0.17677669529663689f * 1.4426950408889634f; // d^-0.5*log2(e)

  pool_kernel<<<BATCH * DIMC, 256, 0, stream>>>(x, xavg);
  conv_all<<<704, 256, 0, stream>>>(x, xavg, q_w, kv_w, proj_w, Xh, Ah, Wth);
  gemm_qkv_hi<<<dim3(36, 12, 2), 128, 0, stream>>>(Wth, q_b, kv_b,
                                                   Xh, Ah, Qhi, Khi, Vhi, qscale);
  attn_fused<<<1152, 256, 0, stream>>>(Qhi, Khi, Vhi, Zh);
  gemm_proj_hi<<<dim3(36, 4, 2), 128, 0, stream>>>(Wth + 196608, proj_b, Zh, out);
}

// Round 11
// 141.466 us; speedup vs baseline: 1.1889x; 1.0021x over previous
//
#include <hip/hip_runtime.h>
#include <hip/hip_bf16.h>
#include <cstdint>

// Problem constants
#define DIMC  256
#define NH    8
#define HD    32
#define NPIX  2304       // 48*48
#define BATCH 2
#define KT    32
#define NWAVE 4          // waves per attn block
#define NTW   18         // k-tiles per wave (72 tiles / 4 waves)
#define KPW   576        // keys per wave (NTW*KT)

typedef short s16x8 __attribute__((ext_vector_type(8)));
typedef short s16x4 __attribute__((ext_vector_type(4)));
typedef float f32x4 __attribute__((ext_vector_type(4)));

#define MFMA32(A,B,C) __builtin_amdgcn_mfma_f32_16x16x32_bf16(A,B,C,0,0,0)

// RNA (round-to-nearest-away) bf16 helpers: 1 VALU each.
__device__ inline uint32_t rnau(float x) { return __float_as_uint(x) + 0x8000u; }
__device__ inline uint32_t pk2(uint32_t l_, uint32_t h_) {
  return __builtin_amdgcn_perm(h_, l_, 0x07060302u);  // lo short=l_, hi short=h_
}

// ---------------------------------------------------------------------------
// Pool: x_avg = (x + box3/9 + box5/25 + box7/49)/4, zero-pad, include_pad
// ---------------------------------------------------------------------------
__global__ __launch_bounds__(256) void pool_kernel(const float* __restrict__ x,
                                                   float* __restrict__ xavg) {
  const int plane = blockIdx.x;
  const float* xp = x + (size_t)plane * NPIX;
  __shared__ float sx[NPIX];
  __shared__ float h3[NPIX], h5[NPIX], h7[NPIX];
  const int t = threadIdx.x;
#pragma unroll
  for (int r = 0; r < 9; ++r) sx[r * 256 + t] = xp[r * 256 + t];
  __syncthreads();
#pragma unroll
  for (int r = 0; r < 9; ++r) {
    int p = r * 256 + t;
    int i = p / 48, j = p - i * 48;
    float a3 = 0.f, a5 = 0.f, a7 = 0.f;
#pragma unroll
    for (int dj = -3; dj <= 3; ++dj) {
      int jj = j + dj;
      if (jj < 0 || jj >= 48) continue;
      float v = sx[i * 48 + jj];
      a7 += v;
      if (dj >= -2 && dj <= 2) a5 += v;
      if (dj >= -1 && dj <= 1) a3 += v;
    }
    h3[p] = a3; h5[p] = a5; h7[p] = a7;
  }
  __syncthreads();
#pragma unroll
  for (int r = 0; r < 9; ++r) {
    int p = r * 256 + t;
    int i = p / 48, j = p - i * 48;
    float b3 = 0.f, b5 = 0.f, b7 = 0.f;
#pragma unroll
    for (int di = -3; di <= 3; ++di) {
      int ii = i + di;
      if (ii < 0 || ii >= 48) continue;
      int q = ii * 48 + j;
      b7 += h7[q];
      if (di >= -2 && di <= 2) b5 += h5[q];
      if (di >= -1 && di <= 1) b3 += h3[q];
    }
    xavg[(size_t)plane * NPIX + p] =
        0.25f * (sx[p] + b3 * (1.f / 9.f) + b5 * (1.f / 25.f) + b7 * (1.f / 49.f));
  }
}

// ---------------------------------------------------------------------------
// Fused converts: blocks 0..287 tconv(x), 288..575 tconv(xavg), 576..703 wconv
// All HI-ONLY. UNCHANGED.
// ---------------------------------------------------------------------------
__global__ __launch_bounds__(256) void conv_all(
    const float* __restrict__ x, const float* __restrict__ xavg,
    const float* __restrict__ qw, const float* __restrict__ kvw,
    const float* __restrict__ pw_,
    short* __restrict__ Xh, short* __restrict__ Ah,
    short* __restrict__ Wth) {
  const int bx = blockIdx.x;
  const int t = threadIdx.x;
  if (bx < 576) {
    const float* src = (bx < 288) ? x : xavg;
    short* dhi = (bx < 288) ? Xh : Ah;
    const int bb = (bx < 288) ? bx : bx - 288;
    const int n0 = (bb % 36) * 64, c0 = ((bb / 36) & 3) * 64, b = bb / 144;
    __shared__ __align__(16) float T[64][68];
    {
      const int c = t >> 2, n4 = (t & 3) * 16;
      const float* sp = src + ((size_t)b * DIMC + c0 + c) * NPIX + n0 + n4;
#pragma unroll
      for (int i2 = 0; i2 < 4; ++i2)
        *(f32x4*)&T[c][n4 + i2 * 4] = *(const f32x4*)(sp + i2 * 4);
    }
    __syncthreads();
    {
      const int n = t >> 2, c4 = (t & 3) * 16;
      float v[16];
#pragma unroll
      for (int i = 0; i < 16; ++i) v[i] = T[c4 + i][n];
      uint32_t a[16];
#pragma unroll
      for (int i = 0; i < 16; ++i) a[i] = rnau(v[i]);
      union { s16x8 s; uint32_t u[4]; } H0, H1;
#pragma unroll
      for (int j = 0; j < 4; ++j) {
        H0.u[j] = pk2(a[2 * j], a[2 * j + 1]);
        H1.u[j] = pk2(a[8 + 2 * j], a[8 + 2 * j + 1]);
      }
      const size_t off = ((size_t)b * NPIX + n0 + n) * DIMC + c0 + c4;
      *(s16x8*)(dhi + off) = H0.s; *(s16x8*)(dhi + off + 8) = H1.s;
    }
  } else {
    const int idx = ((bx - 576) * 256 + t) * 8;
    const float* s;
    int off;
    if (idx < 65536)       { s = qw;  off = idx; }
    else if (idx < 196608) { s = kvw; off = idx - 65536; }
    else                   { s = pw_; off = idx - 196608; }
    f32x4 x0 = *(const f32x4*)(s + off);
    f32x4 x1 = *(const f32x4*)(s + off + 4);
    float v[8] = {x0[0], x0[1], x0[2], x0[3], x1[0], x1[1], x1[2], x1[3]};
    uint32_t a[8];
#pragma unroll
    for (int i = 0; i < 8; ++i) a[i] = rnau(v[i]);
    union { s16x8 s; uint32_t u[4]; } H;
#pragma unroll
    for (int j = 0; j < 4; ++j) H.u[j] = pk2(a[2 * j], a[2 * j + 1]);
    *(s16x8*)(Wth + idx) = H.s;
  }
}

// ---------------------------------------------------------------------------
// QKV GEMM, WIDENED (R8): 64 output channels per block. V epilogue keeps the
// R6 mu-permutation. Bitwise-identical outputs to R6.
// ---------------------------------------------------------------------------
__global__ __launch_bounds__(128) void gemm_qkv_hi(
    const short* __restrict__ Wth,
    const float* __restrict__ q_b, const float* __restrict__ kv_b,
    const short* __restrict__ Xh, const short* __restrict__ Ah,
    short* __restrict__ Qhi, short* __restrict__ Khi, short* __restrict__ Vhi,
    float qscale) {
  __shared__ __align__(16) float Cl[64][68];
  const int by = blockIdx.y;           // 0..11
  const bool isQ = (by < 4);
  const int o0 = isQ ? by * 64 : (by - 4) * 64;   // local Q- or KV-space
  const short* Wh = isQ ? Wth : Wth + 65536;
  const float* bias = isQ ? q_b : kv_b;
  const short* Inh = isQ ? Xh : Ah;
  const float scale = isQ ? qscale : 1.0f;
  short* d1 = isQ ? Qhi : Khi;         // used for Q/K epilogue
  const int n0 = blockIdx.x * 64;
  const int b  = blockIdx.z;

  const int tid = threadIdx.x;
  const int wave = tid >> 6, lane = tid & 63;
  const int g = lane >> 4, q = lane & 15;

  const short* wph = Wh + ((o0 + wave * 32 + q) * DIMC + g * 8);
  const short* iph = Inh + ((size_t)(b * NPIX + n0 + q) * DIMC + g * 8);

  f32x4 acc[2][4] = {{{0,0,0,0},{0,0,0,0},{0,0,0,0},{0,0,0,0}},
                     {{0,0,0,0},{0,0,0,0},{0,0,0,0},{0,0,0,0}}};
#pragma unroll
  for (int c0 = 0; c0 < DIMC; c0 += 32) {
    s16x8 a0 = *(const s16x8*)(wph + c0);
    s16x8 a1 = *(const s16x8*)(wph + 16 * DIMC + c0);
#pragma unroll
    for (int st = 0; st < 4; ++st) {
      s16x8 bh_ = *(const s16x8*)(iph + (size_t)st * 16 * DIMC + c0);
      acc[0][st] = MFMA32(a0, bh_, acc[0][st]);
      acc[1][st] = MFMA32(a1, bh_, acc[1][st]);
    }
  }
#pragma unroll
  for (int a16 = 0; a16 < 2; ++a16)
#pragma unroll
    for (int st = 0; st < 4; ++st)
#pragma unroll
      for (int r = 0; r < 4; ++r)
        Cl[wave * 32 + a16 * 16 + g * 4 + r][st * 16 + q] = acc[a16][st][r];
  __syncthreads();

  if (by < 8) {
    // Q or K: (C+bias)*scale, hi-only, layout [bh][n][32]; 64 channels.
    const int n = tid >> 1, oq = tid & 1;
#pragma unroll
    for (int h2 = 0; h2 < 2; ++h2) {
      const int h = (o0 >> 5) + h2;
      const float* bp = bias + o0 + h2 * 32 + oq * 16;
      float v[16];
#pragma unroll
      for (int i = 0; i < 16; ++i)
        v[i] = (Cl[h2 * 32 + oq * 16 + i][n] + bp[i]) * scale;
      uint32_t a[16];
#pragma unroll
      for (int i = 0; i < 16; ++i) a[i] = rnau(v[i]);
      union { s16x8 s; uint32_t u[4]; } H0, H1;
#pragma unroll
      for (int j = 0; j < 4; ++j) {
        H0.u[j] = pk2(a[2 * j], a[2 * j + 1]);
        H1.u[j] = pk2(a[8 + 2 * j], a[8 + 2 * j + 1]);
      }
      const size_t off = ((size_t)((b * 8 + h) * NPIX + n0 + n)) * HD + oq * 16;
      *(s16x8*)(d1 + off) = H0.s; *(s16x8*)(d1 + off + 8) = H1.s;
    }
  } else {
    // V hi-only: dst [bh][d][n], n mu-permuted within each 32-tile; 64 ch.
    const int o = tid >> 2, nc = (tid & 3) * 16;
#pragma unroll
    for (int h2 = 0; h2 < 2; ++h2) {
      const int ch = o0 + h2 * 32 + o;          // 256..511 in KV space
      const int h = (ch - 256) >> 5;
      const float bv = bias[ch];
      float v[16];
#pragma unroll
      for (int i2 = 0; i2 < 4; ++i2) {
        f32x4 t4 = *(const f32x4*)&Cl[h2 * 32 + o][nc + i2 * 4];
        v[i2 * 4 + 0] = t4[0] + bv; v[i2 * 4 + 1] = t4[1] + bv;
        v[i2 * 4 + 2] = t4[2] + bv; v[i2 * 4 + 3] = t4[3] + bv;
      }
      uint32_t a[16];
#pragma unroll
      for (int i = 0; i < 16; ++i) a[i] = rnau(v[i]);
      short* po = Vhi + ((size_t)((b * 8 + h) * HD + o)) * NPIX + n0 + (nc & 32);
      const int phase = (nc & 16) ? 4 : 0;
#pragma unroll
      for (int j = 0; j < 4; ++j) {
        uint2 wv;
        wv.x = pk2(a[4 * j], a[4 * j + 1]);
        wv.y = pk2(a[4 * j + 2], a[4 * j + 3]);
        *(uint2*)(po + phase + 8 * j) = wv;
      }
    }
  }
}

// ---------------------------------------------------------------------------
// MFMA flash attention — R8 VERBATIM (best measured attn: 42.6 us).
// 32 q-rows/block, 4-wave intra-block split-K, in-register P via mu-permuted
// V, XCD swizzle, rnau+pk2 P-pack (R9's cvt_pk asm was −3 us: latency-bound,
// and inline asm hurt scheduling). LDS only for final reduction.
// ---------------------------------------------------------------------------
__global__ __launch_bounds__(256) void attn_fused(
    const short* __restrict__ Qhi,   // [bh][n][32]
    const short* __restrict__ Khi,   // [bh][n][32]
    const short* __restrict__ Vhi,   // [bh][32][N] (n mu-permuted per 32-tile)
    short* __restrict__ zh) {        // [b][pix][256] scrambled
  const int li = blockIdx.x;         // 0..1151
  const int r144 = li >> 3;          // 0..143
  const int bh = 2 * (li & 7) + (r144 >= 72 ? 1 : 0);
  const int qb = (r144 >= 72) ? r144 - 72 : r144;  // 32-row q block
  const int tid = threadIdx.x;
  const int wave = tid >> 6, lane = tid & 63;
  const int g = lane >> 4, q = lane & 15;
  const int base = qb * 32;

  // LDS: final reduction only. [4 waves][64 lanes][20 f32] = 20480 B.
  __shared__ __align__(16) float R[4][64][20];

  const size_t qoff = ((size_t)bh * NPIX + base + q) * HD + g * 8;
  const s16x8 qhA = *(const s16x8*)(Qhi + qoff);
  const s16x8 qhB = *(const s16x8*)(Qhi + qoff + 16 * HD);

  const short* kp = Khi + ((size_t)bh * NPIX + wave * KPW + q) * HD + g * 8;
  const short* vp = Vhi + ((size_t)bh * HD + q) * NPIX + wave * KPW + g * 8;

  const f32x4 Z4 = {0.f, 0.f, 0.f, 0.f};
  f32x4 OA0 = Z4, OA1 = Z4, OB0 = Z4, OB1 = Z4;
  f32x4 LA = Z4, LB = Z4;
  s16x8 kb[3][2], vb[3][2], pfA, pfB, vp0, vp1;

  union { s16x8 s; uint32_t u[4]; } ONE, ZZ;
  ONE.u[0] = 0x3F803F80u; ONE.u[1] = 0x3F803F80u;
  ONE.u[2] = 0x3F803F80u; ONE.u[3] = 0x3F803F80u;
  ZZ.u[0] = 0; ZZ.u[1] = 0; ZZ.u[2] = 0; ZZ.u[3] = 0;
  const s16x8 ones = ONE.s;
  pfA = ZZ.s; pfB = ZZ.s;          // P=0 -> first O/L MFMAs add exact 0
  vp0 = ones; vp1 = ones;          // finite (avoid NaN*0)

  kb[0][0] = *(const s16x8*)(kp);
  kb[0][1] = *(const s16x8*)(kp + 16 * HD);
  vb[0][0] = *(const s16x8*)(vp);
  vb[0][1] = *(const s16x8*)(vp + 16 * NPIX);
  kb[1][0] = *(const s16x8*)(kp + KT * HD);
  kb[1][1] = *(const s16x8*)(kp + KT * HD + 16 * HD);
  vb[1][0] = *(const s16x8*)(vp + KT);
  vb[1][1] = *(const s16x8*)(vp + KT + 16 * NPIX);

#define ATTN_STEP(CUR, NX2, T)                                                \
  {                                                                           \
    if ((T) + 2 < NTW) {                                                      \
      const short* kpn = kp + ((T) + 2) * (KT * HD);                          \
      const short* vpn = vp + ((T) + 2) * KT;                                 \
      kb[NX2][0] = *(const s16x8*)(kpn);                                      \
      kb[NX2][1] = *(const s16x8*)(kpn + 16 * HD);                            \
      vb[NX2][0] = *(const s16x8*)(vpn);                                      \
      vb[NX2][1] = *(const s16x8*)(vpn + 16 * NPIX);                          \
    }                                                                         \
    f32x4 SA0 = MFMA32(kb[CUR][0], qhA, Z4);                                  \
    f32x4 SA1 = MFMA32(kb[CUR][1], qhA, Z4);                                  \
    f32x4 SB0 = MFMA32(kb[CUR][0], qhB, Z4);                                  \
    f32x4 SB1 = MFMA32(kb[CUR][1], qhB, Z4);                                  \
    OA0 = MFMA32(vp0, pfA, OA0);                                              \
    OA1 = MFMA32(vp1, pfA, OA1);                                              \
    OB0 = MFMA32(vp0, pfB, OB0);                                              \
    OB1 = MFMA32(vp1, pfB, OB1);                                              \
    LA  = MFMA32(ones, pfA, LA);                                              \
    LB  = MFMA32(ones, pfB, LB);                                              \
    {                                                                         \
      f32x4 p0, p1;                                                           \
      p0[0] = exp2f(SA0[0]); p0[1] = exp2f(SA0[1]);                           \
      p0[2] = exp2f(SA0[2]); p0[3] = exp2f(SA0[3]);                           \
      p1[0] = exp2f(SA1[0]); p1[1] = exp2f(SA1[1]);                           \
      p1[2] = exp2f(SA1[2]); p1[3] = exp2f(SA1[3]);                           \
      union { s16x8 s; uint32_t u[4]; } PA;                                   \
      PA.u[0] = pk2(rnau(p0[0]), rnau(p0[1]));                                \
      PA.u[1] = pk2(rnau(p0[2]), rnau(p0[3]));                                \
      PA.u[2] = pk2(rnau(p1[0]), rnau(p1[1]));                                \
      PA.u[3] = pk2(rnau(p1[2]), rnau(p1[3]));                                \
      pfA = PA.s;                                                             \
    }                                                                         \
    {                                                                         \
      f32x4 p0, p1;                                                           \
      p0[0] = exp2f(SB0[0]); p0[1] = exp2f(SB0[1]);                           \
      p0[2] = exp2f(SB0[2]); p0[3] = exp2f(SB0[3]);                           \
      p1[0] = exp2f(SB1[0]); p1[1] = exp2f(SB1[1]);                           \
      p1[2] = exp2f(SB1[2]); p1[3] = exp2f(SB1[3]);                           \
      union { s16x8 s; uint32_t u[4]; } PB;                                   \
      PB.u[0] = pk2(rnau(p0[0]), rnau(p0[1]));                                \
      PB.u[1] = pk2(rnau(p0[2]), rnau(p0[3]));                                \
      PB.u[2] = pk2(rnau(p1[0]), rnau(p1[1]));                                \
      PB.u[3] = pk2(rnau(p1[2]), rnau(p1[3]));                                \
      pfB = PB.s;                                                             \
    }                                                                         \
    vp0 = vb[CUR][0]; vp1 = vb[CUR][1];                                       \
  }

#pragma unroll 1
  for (int tt = 0; tt < NTW; tt += 3) {
    ATTN_STEP(0, 2, tt);
    ATTN_STEP(1, 0, tt + 1);
    ATTN_STEP(2, 1, tt + 2);
  }
#undef ATTN_STEP

  // Tail: consume P of the wave's last tile
  OA0 = MFMA32(vp0, pfA, OA0);
  OA1 = MFMA32(vp1, pfA, OA1);
  OB0 = MFMA32(vp0, pfB, OB0);
  OB1 = MFMA32(vp1, pfB, OB1);
  LA  = MFMA32(ones, pfA, LA);
  LB  = MFMA32(ones, pfB, LB);

  {
    float* rw = &R[wave][lane][0];
    *(f32x4*)&rw[0]  = OA0;   // d = g*4+r        (rows nA)
    *(f32x4*)&rw[4]  = OA1;   // d = 16+g*4+r
    *(f32x4*)&rw[8]  = OB0;   // d = g*4+r        (rows nB)
    *(f32x4*)&rw[12] = OB1;   // d = 16+g*4+r
    rw[16] = LA[0];           // L rows identical -> LA[0] = L[q-row A]
    rw[17] = LB[0];
  }
  __syncthreads();
  {
    // 256 threads: lane-slot l2, element group eg (4 O-elems each).
    const int l2 = tid & 63, eg = tid >> 6;
    const int g2 = l2 >> 4, q2 = l2 & 15;
    f32x4 s = {0.f, 0.f, 0.f, 0.f};
    float Lt = 0.f;
#pragma unroll
    for (int w = 0; w < NWAVE; ++w) {
      const f32x4 pv = *(const f32x4*)&R[w][l2][eg * 4];
      s[0] += pv[0]; s[1] += pv[1]; s[2] += pv[2]; s[3] += pv[3];
      Lt += R[w][l2][16 + (eg >> 1)];
    }
    const float inv = 1.f / Lt;
    const int h = bh & 7, b = bh >> 3;
    const int n = base + ((eg & 2) ? 16 : 0) + q2;
    const int d0 = ((eg & 1) ? 16 : 0) + g2 * 4;
    const int c = n / 9, r = n - c * 9;
    short* zp = zh + ((size_t)(b * NPIX + r * 256 + h * HD + d0)) * DIMC + c;
#pragma unroll
    for (int j = 0; j < 4; ++j)
      zp[(size_t)j * DIMC] = (short)(rnau(s[j] * inv) >> 16);
  }
}

// ---------------------------------------------------------------------------
// PROJ GEMM, WIDENED (R8): 64 output channels per block. UNCHANGED.
// ---------------------------------------------------------------------------
__global__ __launch_bounds__(128) void gemm_proj_hi(
    const short* __restrict__ Wh,
    const float* __restrict__ bias,
    const short* __restrict__ Zh,
    float* __restrict__ out) {
  __shared__ __align__(16) float Cl[64][68];
  const int n0 = blockIdx.x * 64;
  const int o0 = blockIdx.y * 64;
  const int b  = blockIdx.z;
  const int tid = threadIdx.x;
  const int wave = tid >> 6, lane = tid & 63;
  const int g = lane >> 4, q = lane & 15;

  const short* wph = Wh + ((o0 + wave * 32 + q) * DIMC + g * 8);
  const short* iph = Zh + ((size_t)(b * NPIX + n0 + q) * DIMC + g * 8);

  f32x4 acc[2][4] = {{{0,0,0,0},{0,0,0,0},{0,0,0,0},{0,0,0,0}},
                     {{0,0,0,0},{0,0,0,0},{0,0,0,0},{0,0,0,0}}};
#pragma unroll
  for (int c0 = 0; c0 < DIMC; c0 += 32) {
    s16x8 a0 = *(const s16x8*)(wph + c0);
    s16x8 a1 = *(const s16x8*)(wph + 16 * DIMC + c0);
#pragma unroll
    for (int st = 0; st < 4; ++st) {
      s16x8 bh_ = *(const s16x8*)(iph + (size_t)st * 16 * DIMC + c0);
      acc[0][st] = MFMA32(a0, bh_, acc[0][st]);
      acc[1][st] = MFMA32(a1, bh_, acc[1][st]);
    }
  }
#pragma unroll
  for (int a16 = 0; a16 < 2; ++a16)
#pragma unroll
    for (int st = 0; st < 4; ++st)
#pragma unroll
      for (int r = 0; r < 4; ++r)
        Cl[wave * 32 + a16 * 16 + g * 4 + r][st * 16 + q] = acc[a16][st][r];
  __syncthreads();

  const int o = tid >> 2, nc = (tid & 3) * 16;
#pragma unroll
  for (int h2 = 0; h2 < 2; ++h2) {
    const int row = h2 * 32 + o;
    const float bv = bias[o0 + row];
    float* op = out + ((size_t)b * DIMC + o0 + row) * NPIX + n0 + nc;
#pragma unroll
    for (int i2 = 0; i2 < 4; ++i2) {
      f32x4 v = *(const f32x4*)&Cl[row][nc + i2 * 4];
      v[0] += bv; v[1] += bv; v[2] += bv; v[3] += bv;
      *(f32x4*)(op + i2 * 4) = v;
    }
  }
}

// ---------------------------------------------------------------------------
extern "C" void kernel_launch(void* const* d_in, const int* in_sizes, int n_in,
                              void* d_out, int out_size, void* d_ws, size_t ws_size,
                              hipStream_t stream) {
  const float* x      = (const float*)d_in[0];
  const float* q_w    = (const float*)d_in[1];
  const float* q_b    = (const float*)d_in[2];
  const float* kv_w   = (const float*)d_in[3];
  const float* kv_b   = (const float*)d_in[4];
  const float* proj_w = (const float*)d_in[5];
  const float* proj_b = (const float*)d_in[6];
  float* out = (float*)d_out;

  // Workspace (offsets preserved).
  char* w = (char*)d_ws;
  float* xavg = (float*)w;                       // 4,718,592
  short* Xh   = (short*)(w + 4718592);
  short* Ah   = (short*)(w + 9437184);
  short* Wth  = (short*)(w + 28311552);          // 524,288 (hi only)
  short* Qhi  = (short*)(w + 29360128);          // 2,359,296
  short* Khi  = (short*)(w + 31719424);
  short* Vhi  = (short*)(w + 34078720);
  short* Zh   = (short*)(w + 37322752);          // 2,359,296

  const float qscale = 0.17677669529663689f * 1.4426950408889634f; // d^-0.5*log2(e)

  pool_kernel<<<BATCH * DIMC, 256, 0, stream>>>(x, xavg);
  conv_all<<<704, 256, 0, stream>>>(x, xavg, q_w, kv_w, proj_w, Xh, Ah, Wth);
  gemm_qkv_hi<<<dim3(36, 12, 2), 128, 0, stream>>>(Wth, q_b, kv_b,
                                                   Xh, Ah, Qhi, Khi, Vhi, qscale);
  attn_fused<<<1152, 256, 0, stream>>>(Qhi, Khi, Vhi, Zh);
  gemm_proj_hi<<<dim3(36, 4, 2), 128, 0, stream>>>(Wth + 196608, proj_b, Zh, out);
}